// Round 4
// baseline (595.108 us; speedup 1.0000x reference)
//
#include <hip/hip_runtime.h>
#include <math.h>

#define NV 32768
#define CD 128
#define NCLS 10
#define KSEL 500
#define BNEPS 1e-5f
#define NK (NCLS * NV)            // 327680 keys per batch
#define H1CUT 0x3E00              // score >= 0.125 ; bins (s>>16)-H1CUT in [0,384)
#define H1BINS 384
#define CANDCAP 2048
#define ABLKROWS 64
#define ABLKPERB (NV / ABLKROWS)  // 512 stageA blocks per batch
#define BCHUNKS 32
#define CHUNKSZ (NK / BCHUNKS)    // 10240

// ---------------------------------------------------------------------------
// Stage A helpers
// ---------------------------------------------------------------------------
__device__ __forceinline__ void loadW(float4 w[8], const float* __restrict__ W1,
                                      int kc, int c0) {
    const float* wp = W1 + (kc << 9) + c0;      // kc*4 k-rows, 128 floats each
    #pragma unroll
    for (int kk = 0; kk < 4; ++kk) {
        w[2 * kk]     = *(const float4*)(wp + (kk << 7));
        w[2 * kk + 1] = *(const float4*)(wp + (kk << 7) + 4);
    }
}

__device__ __forceinline__ void computeKC(float acc[4][8], const float4* __restrict__ fsmv,
                                          int r0, int kc, const float4 w[8]) {
    float4 fr[4];
    #pragma unroll
    for (int i = 0; i < 4; ++i) {
        const int row = r0 + i;
        fr[i] = fsmv[row * 32 + (kc ^ (row & 31))];
    }
    const float* frp = (const float*)fr;
    #pragma unroll
    for (int kk = 0; kk < 4; ++kk) {
        const float* wv = (const float*)&w[2 * kk];
        #pragma unroll
        for (int ri = 0; ri < 4; ++ri) {
            const float f = frp[ri * 4 + kk];
            #pragma unroll
            for (int ci = 0; ci < 8; ++ci)
                acc[ri][ci] = fmaf(f, wv[ci], acc[ri][ci]);
        }
    }
}

// ---------------------------------------------------------------------------
// Stage A: hm head over all voxels. 64 rows x 128 cols per block (256 thr),
// 4x8 per-thread micro-tile (R2 structure, measured 126us@38%VALU), plus:
// explicit W1 double-buffered register prefetch (kc+1 loaded during kc compute)
// to stretch the L2 load->use distance. Epilogue identical to R2. Emits
// per-block hist1 partials and zeroes the hist2 fallback region.
// ---------------------------------------------------------------------------
__global__ __launch_bounds__(256, 4) void stageA_kernel(
    const float* __restrict__ feats,
    const float* __restrict__ W1,
    const float* __restrict__ b1,
    const float* __restrict__ bng,
    const float* __restrict__ bnb,
    const float* __restrict__ bnm,
    const float* __restrict__ bnv,
    const float* __restrict__ W2hm,
    const float* __restrict__ b2hm,
    unsigned int* __restrict__ scoreb,
    unsigned int* __restrict__ hist1p,
    unsigned int* __restrict__ hist2)
{
    __shared__ __align__(16) float smem[64 * 129]; // feats (swizzled f4) / act
    __shared__ float w2s[CD * NCLS];
    __shared__ float b2s[NCLS];
    __shared__ unsigned int lhist[H1BINS];
    float4* const fsmv = (float4*)smem;

    const int tid = threadIdx.x;
    const int gbase = blockIdx.x * ABLKROWS;

    // zero this block's hist2 chunk (fallback path scratch): 2048 x 128 words
    if (tid < 128) hist2[blockIdx.x * 128 + tid] = 0u;
    for (int i = tid; i < H1BINS; i += 256) lhist[i] = 0u;
    for (int i = tid; i < CD * NCLS; i += 256) w2s[i] = W2hm[i];
    if (tid < NCLS) b2s[tid] = b2hm[tid];

    // feats tile -> LDS, swizzled: (r, group g) at fsmv[r*32 + (g^(r&31))]
    for (int t = tid; t < ABLKROWS * 32; t += 256) {
        const int r = t >> 5;
        const int g = t & 31;
        const float4 v = *(const float4*)(feats + (((size_t)(gbase + r)) << 7) + (g << 2));
        fsmv[r * 32 + (g ^ (r & 31))] = v;
    }
    __syncthreads();

    const int c0 = (tid & 15) << 3;   // 8 output cols
    const int r0 = (tid >> 4) << 2;   // 4 rows

    float acc[4][8];
    #pragma unroll
    for (int i = 0; i < 4; ++i)
        #pragma unroll
        for (int j = 0; j < 8; ++j) acc[i][j] = 0.f;

    // software-pipelined K loop: W1 for kc+1 prefetched while computing kc
    float4 wA[8], wB[8];
    loadW(wA, W1, 0, c0);
    #pragma unroll 1
    for (int kc = 0; kc < 32; kc += 2) {
        loadW(wB, W1, kc + 1, c0);
        computeKC(acc, fsmv, r0, kc, wA);
        if (kc + 2 < 32) loadW(wA, W1, kc + 2, c0);
        computeKC(acc, fsmv, r0, kc + 1, wB);
    }
    __syncthreads(); // all fsmv reads done before act overwrite

    // BN (eval) + ReLU — identical formulas/order to rounds 1-3
    #pragma unroll
    for (int ci = 0; ci < 8; ++ci) {
        const int c = c0 + ci;
        const float inv = bng[c] / sqrtf(bnv[c] + BNEPS);
        const float mu = bnm[c];
        const float be = bnb[c];
        const float bb = b1[c];
        #pragma unroll
        for (int ri = 0; ri < 4; ++ri) {
            const float h = (acc[ri][ci] + bb - mu) * inv + be;
            acc[ri][ci] = fmaxf(h, 0.f);
        }
    }
    // act[r][c], stride 129 (2-way bank aliasing = free)
    #pragma unroll
    for (int ri = 0; ri < 4; ++ri)
        #pragma unroll
        for (int ci = 0; ci < 8; ++ci)
            smem[(r0 + ri) * 129 + c0 + ci] = acc[ri][ci];
    __syncthreads();

    // GEMM2: logits[r][o] = sum_c act[r][c] * W2[c][o]; sequential c order.
    const int r = tid & 63;
    const int ogrp = tid >> 6;  // wave-uniform
    float lg[3] = {0.f, 0.f, 0.f};
    for (int c = 0; c < 128; ++c) {
        const float a = smem[r * 129 + c];
        #pragma unroll
        for (int i = 0; i < 3; ++i) {
            const int o = ogrp + 4 * i;
            if (o < NCLS) lg[i] = fmaf(a, w2s[c * NCLS + o], lg[i]);
        }
    }
    const int n = gbase + r;
    const int b = n >> 15;          // NV = 2^15
    const int v = n & (NV - 1);
    unsigned int* sb = scoreb + (size_t)b * NK;
    #pragma unroll
    for (int i = 0; i < 3; ++i) {
        const int o = ogrp + 4 * i;
        if (o < NCLS) {
            const float x = lg[i] + b2s[o];
            const float s = 1.f / (1.f + expf(-x));
            const unsigned int u = __float_as_uint(s);
            sb[o * NV + v] = u;
            const int rel = (int)(u >> 16) - H1CUT;
            if (rel >= 0) atomicAdd(&lhist[rel], 1u); // max rel = 383 (s<1.0)
        }
    }
    __syncthreads();
    for (int i = tid; i < H1BINS; i += 256)
        hist1p[(size_t)blockIdx.x * H1BINS + i] = lhist[i];
}

// ---------------------------------------------------------------------------
// B2: per batch, sum 512 partial hists -> t1 cut + g1; zero cnt. grid (B)
// ---------------------------------------------------------------------------
__global__ __launch_bounds__(384) void stageB2_kernel(
    const unsigned int* __restrict__ hist1p,
    unsigned int* __restrict__ t1buf, unsigned int* __restrict__ g1buf,
    unsigned int* __restrict__ cnt)
{
    __shared__ unsigned int histS[H1BINS];
    const int b = blockIdx.x;
    const int tid = threadIdx.x;
    unsigned int sum = 0;
    const unsigned int* hp = hist1p + (size_t)b * ABLKPERB * H1BINS + tid;
    #pragma unroll 8
    for (int j = 0; j < ABLKPERB; ++j) sum += hp[(size_t)j * H1BINS];
    histS[tid] = sum;
    __syncthreads();
    if (tid == 0) {
        cnt[b] = 0;
        int above = 0;
        int c = H1BINS - 1;
        for (; c > 0; --c) {
            if (above + (int)histS[c] >= KSEL) break;
            above += (int)histS[c];
        }
        t1buf[b] = (unsigned int)(c + H1CUT);
        g1buf[b] = (unsigned int)above;   // count of keys with (s>>16) > t1
    }
}

// ---------------------------------------------------------------------------
// B5: wide filter (s>>16) >= t1 into candidate list. grid (BCHUNKS, B)
// ---------------------------------------------------------------------------
__global__ __launch_bounds__(256) void stageB5_kernel(
    const unsigned int* __restrict__ scoreb, const unsigned int* __restrict__ t1buf,
    unsigned int* __restrict__ cnt, unsigned long long* __restrict__ cand)
{
    const int b = blockIdx.y;
    const unsigned int t1 = t1buf[b];
    const int base = blockIdx.x * CHUNKSZ;
    const unsigned int* sb = scoreb + (size_t)b * NK + base;
    for (int i = threadIdx.x; i < CHUNKSZ; i += 256) {
        const unsigned int s = sb[i];
        if ((s >> 16) >= t1) {
            const unsigned int p = atomicAdd(&cnt[b], 1u);
            if (p < CANDCAP)
                cand[(size_t)b * CANDCAP + p] =
                    ((unsigned long long)s << 32) |
                    (unsigned long long)(0xFFFFFFFFu - (unsigned int)(base + i));
        }
    }
}

// ---------------------------------------------------------------------------
// B6: per batch bitonic sort of candidates (desc), emit top-500. Exact
// single-block fallback (hist2 refine + rescan) if cnt overflowed CANDCAP.
// ---------------------------------------------------------------------------
__global__ __launch_bounds__(1024) void stageB6_kernel(
    const unsigned int* __restrict__ scoreb,
    const unsigned int* __restrict__ t1buf, const unsigned int* __restrict__ g1buf,
    const unsigned int* __restrict__ cntg,
    const unsigned long long* __restrict__ candg,
    unsigned int* __restrict__ hist2,
    float* __restrict__ sel_score, int* __restrict__ sel_cls, int* __restrict__ sel_vox)
{
    __shared__ unsigned long long cand[CANDCAP];
    __shared__ unsigned int csum[1024];
    __shared__ int s_cnt;
    __shared__ unsigned int s_T;
    const int b = blockIdx.x;
    const int tid = threadIdx.x;
    const unsigned int* sb = scoreb + (size_t)b * NK;
    int cnt = (int)cntg[b];

    if (cnt <= CANDCAP) {
        for (int i = tid; i < CANDCAP; i += 1024)
            cand[i] = (i < cnt) ? candg[(size_t)b * CANDCAP + i] : 0ull;
        __syncthreads();
    } else {
        // exact fallback: refine inside bin t1 via 16-bit hist2 (never expected)
        const unsigned int t1 = t1buf[b];
        for (int i = tid; i < NK; i += 1024) {
            const unsigned int s = sb[i];
            if ((s >> 16) == t1) atomicAdd(&hist2[(size_t)b * 65536 + (s & 0xFFFFu)], 1u);
        }
        __threadfence();
        __syncthreads();
        {
            const uint4* h4 = (const uint4*)(hist2 + (size_t)b * 65536 + tid * 64);
            unsigned int sum = 0;
            #pragma unroll
            for (int i = 0; i < 16; ++i) { const uint4 v = h4[i]; sum += v.x + v.y + v.z + v.w; }
            csum[tid] = sum;
        }
        __syncthreads();
        if (tid == 0) {
            const int need = KSEL - (int)g1buf[b];
            int above = 0;
            int c = 1023;
            for (; c > 0; --c) {
                if (above + (int)csum[c] >= need) break;
                above += (int)csum[c];
            }
            const unsigned int* h2 = hist2 + (size_t)b * 65536 + c * 64;
            const int need2 = need - above;
            int above2 = 0;
            int j = 63;
            for (; j > 0; --j) {
                if (above2 + (int)h2[j] >= need2) break;
                above2 += (int)h2[j];
            }
            s_T = (t1 << 16) | (unsigned int)(c * 64 + j);
            s_cnt = 0;
        }
        __syncthreads();
        const unsigned int T = s_T;
        for (int i = tid; i < NK; i += 1024) {
            const unsigned int s = sb[i];
            if (s >= T) {
                const int p = atomicAdd(&s_cnt, 1);
                if (p < CANDCAP)
                    cand[p] = ((unsigned long long)s << 32) |
                              (unsigned long long)(0xFFFFFFFFu - (unsigned int)i);
            }
        }
        __syncthreads();
        cnt = min(s_cnt, CANDCAP);
        for (int i = tid; i < CANDCAP; i += 1024) if (i >= cnt) cand[i] = 0ull;
        __syncthreads();
    }

    // bitonic sort, descending (real keys > 0, padding = 0)
    for (int size = 2; size <= CANDCAP; size <<= 1) {
        for (int stride = size >> 1; stride > 0; stride >>= 1) {
            #pragma unroll
            for (int half = 0; half < 2; ++half) {
                const int j = tid + (half << 10);
                const int p = j ^ stride;
                if (p > j) {
                    const unsigned long long a = cand[j];
                    const unsigned long long bb = cand[p];
                    const bool descRegion = ((j & size) == 0);
                    if ((a < bb) == descRegion) { cand[j] = bb; cand[p] = a; }
                }
            }
            __syncthreads();
        }
    }

    if (tid < KSEL) {
        const unsigned long long kk = cand[tid];
        const unsigned int s32 = (unsigned int)(kk >> 32);
        const unsigned int fl = 0xFFFFFFFFu - (unsigned int)(kk & 0xFFFFFFFFull);
        const int idx = b * KSEL + tid;
        sel_score[idx] = __uint_as_float(s32);
        sel_cls[idx] = (int)(fl >> 15);
        sel_vox[idx] = (int)(fl & (NV - 1));
    }
}

// ---------------------------------------------------------------------------
// Stage CD: heads 1..5 + decode + all outputs, 8 selections per block.
// ---------------------------------------------------------------------------
__global__ __launch_bounds__(128) void stageCD_kernel(
    const float* __restrict__ feats,
    const int* __restrict__ voxel_xy,
    const float* __restrict__ sel_score,
    const int* __restrict__ sel_cls,
    const int* __restrict__ sel_vox,
    const float* __restrict__ W1,
    const float* __restrict__ b1,
    const float* __restrict__ bng,
    const float* __restrict__ bnb,
    const float* __restrict__ bnm,
    const float* __restrict__ bnv,
    const float* __restrict__ W2c, const float* __restrict__ b2c,
    const float* __restrict__ W2z, const float* __restrict__ b2z,
    const float* __restrict__ W2d, const float* __restrict__ b2d,
    const float* __restrict__ W2r, const float* __restrict__ b2r,
    const float* __restrict__ W2v, const float* __restrict__ b2v,
    float* __restrict__ out,
    int total)
{
    __shared__ float fs[8][128];
    __shared__ float as_[8][128];
    __shared__ float decs[8][10];
    __shared__ int vsel[8];
    const int tid = threadIdx.x;
    const int s0 = blockIdx.x * 8;

    if (tid < 8) {
        const int s = s0 + tid;
        vsel[tid] = (s / KSEL) * NV + sel_vox[s];
    }
    __syncthreads();
    for (int t = tid; t < 8 * 128; t += 128) {
        const int j = t >> 7;
        const int c = t & 127;
        fs[j][c] = feats[((size_t)vsel[j] << 7) + c];
    }
    __syncthreads();

    const int c = tid;
    for (int head = 1; head <= 5; ++head) {
        float acc[8];
        #pragma unroll
        for (int j = 0; j < 8; ++j) acc[j] = 0.f;
        const float* Wh = W1 + head * (CD * CD);
        #pragma unroll 4
        for (int k = 0; k < 128; ++k) {
            const float w = Wh[(k << 7) + c];
            #pragma unroll
            for (int j = 0; j < 8; ++j) acc[j] = fmaf(fs[j][k], w, acc[j]);
        }
        const int hc = head * CD + c;
        const float inv = bng[hc] / sqrtf(bnv[hc] + BNEPS);
        const float mu = bnm[hc], be = bnb[hc], bb = b1[hc];
        #pragma unroll
        for (int j = 0; j < 8; ++j) {
            const float h = (acc[j] + bb - mu) * inv + be;
            as_[j][c] = fmaxf(h, 0.f);
        }
        __syncthreads();

        const float* w2; const float* bb2; int oc, off; bool ex = false;
        if (head == 1)      { w2 = W2c; bb2 = b2c; oc = 2; off = 0; }
        else if (head == 2) { w2 = W2z; bb2 = b2z; oc = 1; off = 2; }
        else if (head == 3) { w2 = W2d; bb2 = b2d; oc = 3; off = 3; ex = true; }
        else if (head == 4) { w2 = W2r; bb2 = b2r; oc = 2; off = 6; }
        else                { w2 = W2v; bb2 = b2v; oc = 2; off = 8; }

        for (int t = tid; t < 8 * oc; t += 128) {
            const int j = t / oc;
            const int o = t % oc;
            float a = 0.f;
            for (int cc = 0; cc < 128; ++cc) a = fmaf(as_[j][cc], w2[cc * oc + o], a);
            a += bb2[o];
            if (ex) a = expf(a);
            decs[j][off + o] = a;
        }
        __syncthreads();
    }

    if (tid < 8) {
        const int s = s0 + tid;
        const int b = s / KSEL;
        const float score = sel_score[s];
        const int cls = sel_cls[s];
        const int v = sel_vox[s];
        const int n = b * NV + v;
        const float xi = (float)voxel_xy[2 * n];
        const float yi = (float)voxel_xy[2 * n + 1];
        const float cx = decs[tid][0], cy = decs[tid][1], cz = decs[tid][2];
        const float d0 = decs[tid][3], d1 = decs[tid][4], d2 = decs[tid][5];
        const float rc = decs[tid][6], rs = decs[tid][7];
        const float ve0 = decs[tid][8], ve1 = decs[tid][9];
        const float SV = 0.075f * 8.0f;
        const float xs = (xi + cx) * SV + (-54.0f);
        const float ys = (yi + cy) * SV + (-54.0f);
        const float ang = atan2f(rs, rc);
        const bool mk = (xs >= -61.2f) && (ys >= -61.2f) && (cz >= -10.0f) &&
                        (xs <= 61.2f) && (ys <= 61.2f) && (cz <= 10.0f) &&
                        (score > 0.1f);
        const float m = mk ? 1.f : 0.f;
        float* bx = out + (size_t)s * 10;
        bx[0] = xs * m; bx[1] = ys * m; bx[2] = cz * m;
        bx[3] = d0 * m; bx[4] = d1 * m; bx[5] = d2 * m;
        bx[6] = ang * m; bx[7] = ve0 * m; bx[8] = ve1 * m; bx[9] = score * m;
        out[(size_t)total * 10 + s] = mk ? (float)(cls + 1) : 0.f;
        out[(size_t)total * 11 + s] = (float)n;
        out[(size_t)total * 12 + s] = m;
    }
}

extern "C" void kernel_launch(void* const* d_in, const int* in_sizes, int n_in,
                              void* d_out, int out_size, void* d_ws, size_t ws_size,
                              hipStream_t stream) {
    const float* feats   = (const float*)d_in[0];
    const int*   voxelxy = (const int*)d_in[1];
    const float* W1   = (const float*)d_in[2];
    const float* b1   = (const float*)d_in[3];
    const float* bng  = (const float*)d_in[4];
    const float* bnb  = (const float*)d_in[5];
    const float* bnm  = (const float*)d_in[6];
    const float* bnv  = (const float*)d_in[7];
    const float* W2hm = (const float*)d_in[8];
    const float* b2hm = (const float*)d_in[9];
    const float* W2c  = (const float*)d_in[10];
    const float* b2c  = (const float*)d_in[11];
    const float* W2z  = (const float*)d_in[12];
    const float* b2z  = (const float*)d_in[13];
    const float* W2d  = (const float*)d_in[14];
    const float* b2d  = (const float*)d_in[15];
    const float* W2r  = (const float*)d_in[16];
    const float* b2r  = (const float*)d_in[17];
    const float* W2v  = (const float*)d_in[18];
    const float* b2v  = (const float*)d_in[19];

    const int B = in_sizes[0] / (NV * CD);
    const int N = B * NV;
    const int total = B * KSEL;
    const int nblkA = N / ABLKROWS;

    // workspace layout (8-byte aligned chunks)
    char* ws = (char*)d_ws;
    unsigned int* scoreb = (unsigned int*)ws;   ws += (size_t)B * NK * 4;
    unsigned int* hist1p = (unsigned int*)ws;   ws += (size_t)nblkA * H1BINS * 4;
    unsigned int* hist2  = (unsigned int*)ws;   ws += (size_t)B * 65536 * 4;
    unsigned long long* cand = (unsigned long long*)ws; ws += (size_t)B * CANDCAP * 8;
    unsigned int* cnt    = (unsigned int*)ws;   ws += (size_t)((B + 1) & ~1) * 4;
    unsigned int* t1buf  = (unsigned int*)ws;   ws += (size_t)((B + 1) & ~1) * 4;
    unsigned int* g1buf  = (unsigned int*)ws;   ws += (size_t)((B + 1) & ~1) * 4;
    float* sel_score = (float*)ws;              ws += (size_t)total * 4;
    int*   sel_cls   = (int*)ws;                ws += (size_t)total * 4;
    int*   sel_vox   = (int*)ws;                ws += (size_t)total * 4;

    stageA_kernel<<<dim3(nblkA), dim3(256), 0, stream>>>(
        feats, W1, b1, bng, bnb, bnm, bnv, W2hm, b2hm, scoreb, hist1p, hist2);

    stageB2_kernel<<<dim3(B), dim3(384), 0, stream>>>(hist1p, t1buf, g1buf, cnt);
    stageB5_kernel<<<dim3(BCHUNKS, B), dim3(256), 0, stream>>>(scoreb, t1buf, cnt, cand);
    stageB6_kernel<<<dim3(B), dim3(1024), 0, stream>>>(
        scoreb, t1buf, g1buf, cnt, cand, hist2, sel_score, sel_cls, sel_vox);

    stageCD_kernel<<<dim3(total / 8), dim3(128), 0, stream>>>(
        feats, voxelxy, sel_score, sel_cls, sel_vox,
        W1, b1, bng, bnb, bnm, bnv,
        W2c, b2c, W2z, b2z, W2d, b2d, W2r, b2r, W2v, b2v,
        (float*)d_out, total);
}

// Round 5
// 353.304 us; speedup vs baseline: 1.6844x; 1.6844x over previous
//
#include <hip/hip_runtime.h>
#include <math.h>

#define NV 32768
#define CD 128
#define NCLS 10
#define KSEL 500
#define BNEPS 1e-5f
#define NK (NCLS * NV)            // 327680 keys per batch
#define H1CUT 0x3E00              // score >= 0.125 ; bins (s>>16)-H1CUT in [0,384)
#define H1BINS 384
#define CANDCAP 2048
#define ABLKROWS 64
#define ABLKPERB (NV / ABLKROWS)  // 512 stageA blocks per batch
#define BCHUNKS 32
#define CHUNKSZ (NK / BCHUNKS)    // 10240
#define WCHUNK 8                  // k-rows per W1 LDS chunk (4 KB)
#define NWCHUNK (CD / WCHUNK)     // 16

// ---------------------------------------------------------------------------
// Stage A: hm head over all voxels. 64 rows x 128 cols per block (256 thr),
// 4x8 micro-tile (R2 structure: proven 126us). NEW: W1 staged through LDS in
// double-buffered 8-k chunks (coop float4 load + ds_write, prefetched one full
// chunk ahead) — W1 (64KB) can't fit L1, so R2 paid ~200cy L2 latency per kc.
// FMA order identical to R1-R4 -> scores bit-identical -> selection exact.
// Epilogue identical to R2: BN+ReLU, act@stride129, GEMM2, sigmoid, score bits,
// hist1 partials. Also zeroes hist2 (fallback scratch) and cnt.
// ---------------------------------------------------------------------------
__global__ __launch_bounds__(256, 3) void stageA_kernel(
    const float* __restrict__ feats,
    const float* __restrict__ W1,
    const float* __restrict__ b1,
    const float* __restrict__ bng,
    const float* __restrict__ bnb,
    const float* __restrict__ bnm,
    const float* __restrict__ bnv,
    const float* __restrict__ W2hm,
    const float* __restrict__ b2hm,
    unsigned int* __restrict__ scoreb,
    unsigned int* __restrict__ hist1p,
    unsigned int* __restrict__ hist2,
    unsigned int* __restrict__ cnt)
{
    __shared__ __align__(16) float smem[64 * 129];      // feats (f4-swizzled) / act
    __shared__ __align__(16) float wlds[2 * WCHUNK * CD]; // 2 x 4 KB W1 chunks; reused as w2s
    __shared__ float b2s[NCLS];
    __shared__ unsigned int lhist[H1BINS];
    float4* const fsmv = (float4*)smem;

    const int tid = threadIdx.x;
    const int gbase = blockIdx.x * ABLKROWS;

    // zero this block's hist2 slice (fallback scratch): nblkA x 128 words
    if (tid < 128) hist2[blockIdx.x * 128 + tid] = 0u;
    if (blockIdx.x == 0 && tid < 8) cnt[tid] = 0u;
    for (int i = tid; i < H1BINS; i += 256) lhist[i] = 0u;
    if (tid < NCLS) b2s[tid] = b2hm[tid];

    // feats tile -> LDS, swizzled: (r, group g) at fsmv[r*32 + (g^(r&31))]
    for (int t = tid; t < ABLKROWS * 32; t += 256) {
        const int r = t >> 5;
        const int g = t & 31;
        const float4 v = *(const float4*)(feats + (((size_t)(gbase + r)) << 7) + (g << 2));
        fsmv[r * 32 + (g ^ (r & 31))] = v;
    }

    const int c0 = (tid & 15) << 3;   // 8 output cols
    const int r0 = (tid >> 4) << 2;   // 4 rows

    float acc[4][8];
    #pragma unroll
    for (int i = 0; i < 4; ++i)
        #pragma unroll
        for (int j = 0; j < 8; ++j) acc[i][j] = 0.f;

    // ---- K loop with double-buffered W1 LDS staging ----
    const float4* Wg = (const float4*)W1;        // head 0, 64 KB = 4096 float4
    float4 wpre = Wg[tid];                       // chunk 0 (1 float4/thread = 4 KB)
    ((float4*)wlds)[tid] = wpre;                 // into buffer 0

    #pragma unroll 1
    for (int ch = 0; ch < NWCHUNK; ++ch) {
        if (ch + 1 < NWCHUNK) wpre = Wg[(ch + 1) * 256 + tid];   // prefetch next
        __syncthreads();                                          // buf[ch&1] ready
        const float* wbuf = wlds + (ch & 1) * (WCHUNK * CD);
        #pragma unroll
        for (int j = 0; j < 2; ++j) {            // two kc (4-k groups) per chunk
            const int kc = ch * 2 + j;
            float4 fr[4];
            #pragma unroll
            for (int i = 0; i < 4; ++i) {
                const int row = r0 + i;
                fr[i] = fsmv[row * 32 + (kc ^ (row & 31))];
            }
            const float* frp = (const float*)fr;
            #pragma unroll
            for (int kk = 0; kk < 4; ++kk) {
                const int kl = j * 4 + kk;       // k within chunk
                const float4 wa = *(const float4*)&wbuf[kl * CD + c0];
                const float4 wb = *(const float4*)&wbuf[kl * CD + c0 + 4];
                const float w[8] = {wa.x, wa.y, wa.z, wa.w, wb.x, wb.y, wb.z, wb.w};
                #pragma unroll
                for (int ri = 0; ri < 4; ++ri) {
                    const float f = frp[ri * 4 + kk];
                    #pragma unroll
                    for (int ci = 0; ci < 8; ++ci)
                        acc[ri][ci] = fmaf(f, w[ci], acc[ri][ci]);
                }
            }
        }
        if (ch + 1 < NWCHUNK)
            ((float4*)(wlds + ((ch + 1) & 1) * (WCHUNK * CD)))[tid] = wpre;
    }
    __syncthreads(); // all fsmv + wlds reads done before overwrite

    // BN (eval) + ReLU — identical formulas/order to rounds 1-4
    #pragma unroll
    for (int ci = 0; ci < 8; ++ci) {
        const int c = c0 + ci;
        const float inv = bng[c] / sqrtf(bnv[c] + BNEPS);
        const float mu = bnm[c];
        const float be = bnb[c];
        const float bb = b1[c];
        #pragma unroll
        for (int ri = 0; ri < 4; ++ri) {
            const float h = (acc[ri][ci] + bb - mu) * inv + be;
            acc[ri][ci] = fmaxf(h, 0.f);
        }
    }
    // act[r][c], stride 129 (2-way bank aliasing = free)
    #pragma unroll
    for (int ri = 0; ri < 4; ++ri)
        #pragma unroll
        for (int ci = 0; ci < 8; ++ci)
            smem[(r0 + ri) * 129 + c0 + ci] = acc[ri][ci];

    // w2s into the (now free) wlds area: 1280 floats <= 2048 capacity
    float* const w2s = wlds;
    for (int i = tid; i < CD * NCLS; i += 256) w2s[i] = W2hm[i];
    __syncthreads();

    // GEMM2: logits[r][o] = sum_c act[r][c] * W2[c][o]; sequential c order.
    const int r = tid & 63;
    const int ogrp = tid >> 6;  // wave-uniform
    float lg[3] = {0.f, 0.f, 0.f};
    for (int c = 0; c < 128; ++c) {
        const float a = smem[r * 129 + c];
        #pragma unroll
        for (int i = 0; i < 3; ++i) {
            const int o = ogrp + 4 * i;
            if (o < NCLS) lg[i] = fmaf(a, w2s[c * NCLS + o], lg[i]);
        }
    }
    const int n = gbase + r;
    const int b = n >> 15;          // NV = 2^15
    const int v = n & (NV - 1);
    unsigned int* sb = scoreb + (size_t)b * NK;
    #pragma unroll
    for (int i = 0; i < 3; ++i) {
        const int o = ogrp + 4 * i;
        if (o < NCLS) {
            const float x = lg[i] + b2s[o];
            const float s = 1.f / (1.f + expf(-x));
            const unsigned int u = __float_as_uint(s);
            sb[o * NV + v] = u;
            const int rel = (int)(u >> 16) - H1CUT;
            if (rel >= 0) atomicAdd(&lhist[rel], 1u); // max rel = 383 (s < 1.0)
        }
    }
    __syncthreads();
    for (int i = tid; i < H1BINS; i += 256)
        hist1p[(size_t)blockIdx.x * H1BINS + i] = lhist[i];
}

// ---------------------------------------------------------------------------
// B5': fused t1-compute + wide filter. grid (BCHUNKS, B), 384 threads.
// Each block deterministically recomputes the batch hist-sum -> t1, then
// filters its chunk: (s>>16) >= t1 into the candidate list.
// ---------------------------------------------------------------------------
__global__ __launch_bounds__(384) void stageB5_kernel(
    const unsigned int* __restrict__ scoreb,
    const unsigned int* __restrict__ hist1p,
    unsigned int* __restrict__ cnt, unsigned long long* __restrict__ cand)
{
    __shared__ unsigned int histS[H1BINS];
    __shared__ unsigned int s_t1;
    const int b = blockIdx.y;
    const int tid = threadIdx.x;

    {   // sum this batch's partial hists (coalesced across tid per j)
        unsigned int sum = 0;
        const unsigned int* hp = hist1p + (size_t)b * ABLKPERB * H1BINS + tid;
        #pragma unroll 8
        for (int j = 0; j < ABLKPERB; ++j) sum += hp[(size_t)j * H1BINS];
        histS[tid] = sum;
    }
    __syncthreads();
    if (tid == 0) {
        int above = 0;
        int c = H1BINS - 1;
        for (; c > 0; --c) {
            if (above + (int)histS[c] >= KSEL) break;
            above += (int)histS[c];
        }
        s_t1 = (unsigned int)(c + H1CUT);
    }
    __syncthreads();
    const unsigned int t1 = s_t1;

    const int base = blockIdx.x * CHUNKSZ;
    const unsigned int* sb = scoreb + (size_t)b * NK + base;
    for (int i = tid; i < CHUNKSZ; i += 384) {
        const unsigned int s = sb[i];
        if ((s >> 16) >= t1) {
            const unsigned int p = atomicAdd(&cnt[b], 1u);
            if (p < CANDCAP)
                cand[(size_t)b * CANDCAP + p] =
                    ((unsigned long long)s << 32) |
                    (unsigned long long)(0xFFFFFFFFu - (unsigned int)(base + i));
        }
    }
}

// ---------------------------------------------------------------------------
// B6: per batch bitonic sort of candidates (desc), emit top-500. Exact
// single-block fallback (t1 recompute + hist2 refine + rescan) if overflow.
// ---------------------------------------------------------------------------
__global__ __launch_bounds__(1024) void stageB6_kernel(
    const unsigned int* __restrict__ scoreb,
    const unsigned int* __restrict__ hist1p,
    const unsigned int* __restrict__ cntg,
    const unsigned long long* __restrict__ candg,
    unsigned int* __restrict__ hist2,
    float* __restrict__ sel_score, int* __restrict__ sel_cls, int* __restrict__ sel_vox)
{
    __shared__ unsigned long long cand[CANDCAP];
    __shared__ unsigned int csum[1024];
    __shared__ unsigned int histS[H1BINS];
    __shared__ int s_cnt;
    __shared__ unsigned int s_T;
    const int b = blockIdx.x;
    const int tid = threadIdx.x;
    const unsigned int* sb = scoreb + (size_t)b * NK;
    int cnt = (int)cntg[b];

    if (cnt <= CANDCAP) {
        for (int i = tid; i < CANDCAP; i += 1024)
            cand[i] = (i < cnt) ? candg[(size_t)b * CANDCAP + i] : 0ull;
        __syncthreads();
    } else {
        // fallback (statistically never taken): recompute t1/g1, refine via hist2
        if (tid < H1BINS) {
            unsigned int sum = 0;
            const unsigned int* hp = hist1p + (size_t)b * ABLKPERB * H1BINS + tid;
            for (int j = 0; j < ABLKPERB; ++j) sum += hp[(size_t)j * H1BINS];
            histS[tid] = sum;
        }
        __syncthreads();
        unsigned int t1 = 0, g1 = 0;
        if (tid == 0) {
            int above = 0;
            int c = H1BINS - 1;
            for (; c > 0; --c) {
                if (above + (int)histS[c] >= KSEL) break;
                above += (int)histS[c];
            }
            s_T = (unsigned int)(c + H1CUT);   // temp reuse: t1
            s_cnt = above;                      // temp reuse: g1
        }
        __syncthreads();
        t1 = s_T; g1 = (unsigned int)s_cnt;
        __syncthreads();
        for (int i = tid; i < NK; i += 1024) {
            const unsigned int s = sb[i];
            if ((s >> 16) == t1) atomicAdd(&hist2[(size_t)b * 65536 + (s & 0xFFFFu)], 1u);
        }
        __threadfence();
        __syncthreads();
        {
            const uint4* h4 = (const uint4*)(hist2 + (size_t)b * 65536 + tid * 64);
            unsigned int sum = 0;
            #pragma unroll
            for (int i = 0; i < 16; ++i) { const uint4 v = h4[i]; sum += v.x + v.y + v.z + v.w; }
            csum[tid] = sum;
        }
        __syncthreads();
        if (tid == 0) {
            const int need = KSEL - (int)g1;
            int above = 0;
            int c = 1023;
            for (; c > 0; --c) {
                if (above + (int)csum[c] >= need) break;
                above += (int)csum[c];
            }
            const unsigned int* h2 = hist2 + (size_t)b * 65536 + c * 64;
            const int need2 = need - above;
            int above2 = 0;
            int j = 63;
            for (; j > 0; --j) {
                if (above2 + (int)h2[j] >= need2) break;
                above2 += (int)h2[j];
            }
            s_T = (t1 << 16) | (unsigned int)(c * 64 + j);
            s_cnt = 0;
        }
        __syncthreads();
        const unsigned int T = s_T;
        for (int i = tid; i < NK; i += 1024) {
            const unsigned int s = sb[i];
            if (s >= T) {
                const int p = atomicAdd(&s_cnt, 1);
                if (p < CANDCAP)
                    cand[p] = ((unsigned long long)s << 32) |
                              (unsigned long long)(0xFFFFFFFFu - (unsigned int)i);
            }
        }
        __syncthreads();
        cnt = min(s_cnt, CANDCAP);
        for (int i = tid; i < CANDCAP; i += 1024) if (i >= cnt) cand[i] = 0ull;
        __syncthreads();
    }

    // bitonic sort, descending (real keys > 0, padding = 0)
    for (int size = 2; size <= CANDCAP; size <<= 1) {
        for (int stride = size >> 1; stride > 0; stride >>= 1) {
            #pragma unroll
            for (int half = 0; half < 2; ++half) {
                const int j = tid + (half << 10);
                const int p = j ^ stride;
                if (p > j) {
                    const unsigned long long a = cand[j];
                    const unsigned long long bb = cand[p];
                    const bool descRegion = ((j & size) == 0);
                    if ((a < bb) == descRegion) { cand[j] = bb; cand[p] = a; }
                }
            }
            __syncthreads();
        }
    }

    if (tid < KSEL) {
        const unsigned long long kk = cand[tid];
        const unsigned int s32 = (unsigned int)(kk >> 32);
        const unsigned int fl = 0xFFFFFFFFu - (unsigned int)(kk & 0xFFFFFFFFull);
        const int idx = b * KSEL + tid;
        sel_score[idx] = __uint_as_float(s32);
        sel_cls[idx] = (int)(fl >> 15);
        sel_vox[idx] = (int)(fl & (NV - 1));
    }
}

// ---------------------------------------------------------------------------
// Stage CD: heads 1..5 + decode + all outputs, 8 selections per block.
// ---------------------------------------------------------------------------
__global__ __launch_bounds__(128) void stageCD_kernel(
    const float* __restrict__ feats,
    const int* __restrict__ voxel_xy,
    const float* __restrict__ sel_score,
    const int* __restrict__ sel_cls,
    const int* __restrict__ sel_vox,
    const float* __restrict__ W1,
    const float* __restrict__ b1,
    const float* __restrict__ bng,
    const float* __restrict__ bnb,
    const float* __restrict__ bnm,
    const float* __restrict__ bnv,
    const float* __restrict__ W2c, const float* __restrict__ b2c,
    const float* __restrict__ W2z, const float* __restrict__ b2z,
    const float* __restrict__ W2d, const float* __restrict__ b2d,
    const float* __restrict__ W2r, const float* __restrict__ b2r,
    const float* __restrict__ W2v, const float* __restrict__ b2v,
    float* __restrict__ out,
    int total)
{
    __shared__ float fs[8][128];
    __shared__ float as_[8][128];
    __shared__ float decs[8][10];
    __shared__ int vsel[8];
    const int tid = threadIdx.x;
    const int s0 = blockIdx.x * 8;

    if (tid < 8) {
        const int s = s0 + tid;
        vsel[tid] = (s / KSEL) * NV + sel_vox[s];
    }
    __syncthreads();
    for (int t = tid; t < 8 * 128; t += 128) {
        const int j = t >> 7;
        const int c = t & 127;
        fs[j][c] = feats[((size_t)vsel[j] << 7) + c];
    }
    __syncthreads();

    const int c = tid;
    for (int head = 1; head <= 5; ++head) {
        float acc[8];
        #pragma unroll
        for (int j = 0; j < 8; ++j) acc[j] = 0.f;
        const float* Wh = W1 + head * (CD * CD);
        #pragma unroll 4
        for (int k = 0; k < 128; ++k) {
            const float w = Wh[(k << 7) + c];
            #pragma unroll
            for (int j = 0; j < 8; ++j) acc[j] = fmaf(fs[j][k], w, acc[j]);
        }
        const int hc = head * CD + c;
        const float inv = bng[hc] / sqrtf(bnv[hc] + BNEPS);
        const float mu = bnm[hc], be = bnb[hc], bb = b1[hc];
        #pragma unroll
        for (int j = 0; j < 8; ++j) {
            const float h = (acc[j] + bb - mu) * inv + be;
            as_[j][c] = fmaxf(h, 0.f);
        }
        __syncthreads();

        const float* w2; const float* bb2; int oc, off; bool ex = false;
        if (head == 1)      { w2 = W2c; bb2 = b2c; oc = 2; off = 0; }
        else if (head == 2) { w2 = W2z; bb2 = b2z; oc = 1; off = 2; }
        else if (head == 3) { w2 = W2d; bb2 = b2d; oc = 3; off = 3; ex = true; }
        else if (head == 4) { w2 = W2r; bb2 = b2r; oc = 2; off = 6; }
        else                { w2 = W2v; bb2 = b2v; oc = 2; off = 8; }

        for (int t = tid; t < 8 * oc; t += 128) {
            const int j = t / oc;
            const int o = t % oc;
            float a = 0.f;
            for (int cc = 0; cc < 128; ++cc) a = fmaf(as_[j][cc], w2[cc * oc + o], a);
            a += bb2[o];
            if (ex) a = expf(a);
            decs[j][off + o] = a;
        }
        __syncthreads();
    }

    if (tid < 8) {
        const int s = s0 + tid;
        const int b = s / KSEL;
        const float score = sel_score[s];
        const int cls = sel_cls[s];
        const int v = sel_vox[s];
        const int n = b * NV + v;
        const float xi = (float)voxel_xy[2 * n];
        const float yi = (float)voxel_xy[2 * n + 1];
        const float cx = decs[tid][0], cy = decs[tid][1], cz = decs[tid][2];
        const float d0 = decs[tid][3], d1 = decs[tid][4], d2 = decs[tid][5];
        const float rc = decs[tid][6], rs = decs[tid][7];
        const float ve0 = decs[tid][8], ve1 = decs[tid][9];
        const float SV = 0.075f * 8.0f;
        const float xs = (xi + cx) * SV + (-54.0f);
        const float ys = (yi + cy) * SV + (-54.0f);
        const float ang = atan2f(rs, rc);
        const bool mk = (xs >= -61.2f) && (ys >= -61.2f) && (cz >= -10.0f) &&
                        (xs <= 61.2f) && (ys <= 61.2f) && (cz <= 10.0f) &&
                        (score > 0.1f);
        const float m = mk ? 1.f : 0.f;
        float* bx = out + (size_t)s * 10;
        bx[0] = xs * m; bx[1] = ys * m; bx[2] = cz * m;
        bx[3] = d0 * m; bx[4] = d1 * m; bx[5] = d2 * m;
        bx[6] = ang * m; bx[7] = ve0 * m; bx[8] = ve1 * m; bx[9] = score * m;
        out[(size_t)total * 10 + s] = mk ? (float)(cls + 1) : 0.f;
        out[(size_t)total * 11 + s] = (float)n;
        out[(size_t)total * 12 + s] = m;
    }
}

extern "C" void kernel_launch(void* const* d_in, const int* in_sizes, int n_in,
                              void* d_out, int out_size, void* d_ws, size_t ws_size,
                              hipStream_t stream) {
    const float* feats   = (const float*)d_in[0];
    const int*   voxelxy = (const int*)d_in[1];
    const float* W1   = (const float*)d_in[2];
    const float* b1   = (const float*)d_in[3];
    const float* bng  = (const float*)d_in[4];
    const float* bnb  = (const float*)d_in[5];
    const float* bnm  = (const float*)d_in[6];
    const float* bnv  = (const float*)d_in[7];
    const float* W2hm = (const float*)d_in[8];
    const float* b2hm = (const float*)d_in[9];
    const float* W2c  = (const float*)d_in[10];
    const float* b2c  = (const float*)d_in[11];
    const float* W2z  = (const float*)d_in[12];
    const float* b2z  = (const float*)d_in[13];
    const float* W2d  = (const float*)d_in[14];
    const float* b2d  = (const float*)d_in[15];
    const float* W2r  = (const float*)d_in[16];
    const float* b2r  = (const float*)d_in[17];
    const float* W2v  = (const float*)d_in[18];
    const float* b2v  = (const float*)d_in[19];

    const int B = in_sizes[0] / (NV * CD);
    const int N = B * NV;
    const int total = B * KSEL;
    const int nblkA = N / ABLKROWS;

    // workspace layout (8-byte aligned chunks)
    char* ws = (char*)d_ws;
    unsigned int* scoreb = (unsigned int*)ws;   ws += (size_t)B * NK * 4;
    unsigned int* hist1p = (unsigned int*)ws;   ws += (size_t)nblkA * H1BINS * 4;
    unsigned int* hist2  = (unsigned int*)ws;   ws += (size_t)B * 65536 * 4;
    unsigned long long* cand = (unsigned long long*)ws; ws += (size_t)B * CANDCAP * 8;
    unsigned int* cnt    = (unsigned int*)ws;   ws += 8 * 4;
    float* sel_score = (float*)ws;              ws += (size_t)total * 4;
    int*   sel_cls   = (int*)ws;                ws += (size_t)total * 4;
    int*   sel_vox   = (int*)ws;                ws += (size_t)total * 4;

    stageA_kernel<<<dim3(nblkA), dim3(256), 0, stream>>>(
        feats, W1, b1, bng, bnb, bnm, bnv, W2hm, b2hm, scoreb, hist1p, hist2, cnt);

    stageB5_kernel<<<dim3(BCHUNKS, B), dim3(384), 0, stream>>>(
        scoreb, hist1p, cnt, cand);
    stageB6_kernel<<<dim3(B), dim3(1024), 0, stream>>>(
        scoreb, hist1p, cnt, cand, hist2, sel_score, sel_cls, sel_vox);

    stageCD_kernel<<<dim3(total / 8), dim3(128), 0, stream>>>(
        feats, voxelxy, sel_score, sel_cls, sel_vox,
        W1, b1, bng, bnb, bnm, bnv,
        W2c, b2c, W2z, b2z, W2d, b2d, W2r, b2r, W2v, b2v,
        (float*)d_out, total);
}